// Round 1
// baseline (1330.563 us; speedup 1.0000x reference)
//
#include <hip/hip_runtime.h>
#include <math.h>

#define D 128

// ---------------- preprocessing ----------------

__global__ __launch_bounds__(256) void count_kernel(
    const int* __restrict__ dst, const float* __restrict__ ew,
    int* __restrict__ deg, float* __restrict__ sacc, int E)
{
    int e = blockIdx.x * 256 + threadIdx.x;
    if (e < E) {
        int d = dst[e];
        atomicAdd(&deg[d], 1);
        atomicAdd(&sacc[d], ew[e]);
    }
}

__global__ __launch_bounds__(1024) void scan_kernel(
    const int* __restrict__ deg, int* __restrict__ row_off,
    int* __restrict__ cursor, int n)
{
    __shared__ int sm[1024];
    int tid = threadIdx.x;
    int carry = 0;
    for (int base = 0; base < n; base += 1024) {
        int i = base + tid;
        int v = (i < n) ? deg[i] : 0;
        sm[tid] = v;
        __syncthreads();
        for (int off = 1; off < 1024; off <<= 1) {
            int t = (tid >= off) ? sm[tid - off] : 0;
            __syncthreads();
            sm[tid] += t;
            __syncthreads();
        }
        int incl = sm[tid];
        if (i < n) {
            int excl = carry + incl - v;
            row_off[i] = excl;
            cursor[i]  = excl;
        }
        int total = sm[1023];
        __syncthreads();
        carry += total;
    }
    if (tid == 0) row_off[n] = carry;
}

__global__ __launch_bounds__(256) void scatter_kernel(
    const int* __restrict__ src, const int* __restrict__ dst,
    const float* __restrict__ ew, int* __restrict__ cursor,
    int* __restrict__ src_s, float* __restrict__ ew_s, int E)
{
    int e = blockIdx.x * 256 + threadIdx.x;
    if (e < E) {
        int d = dst[e];
        int pos = atomicAdd(&cursor[d], 1);
        src_s[pos] = src[e];
        ew_s[pos]  = ew[e];
    }
}

// ---------------- fused 3-matmul per layer ----------------
// a_out[n]    = W1 h[n] + b1
// base_out[n] = (W3 h[n] + b3) - s[n] * (W2 h[n])
// block: 256 threads, 64 nodes; thread tile 4 nodes x 8 outs

__global__ __launch_bounds__(256) void gemm_kernel(
    const float* __restrict__ in, const float* __restrict__ W1,
    const float* __restrict__ b1, const float* __restrict__ W2,
    const float* __restrict__ W3, const float* __restrict__ b3,
    const float* __restrict__ sdeg, float* __restrict__ a_out,
    float* __restrict__ base_out, int N)
{
    __shared__ float Hs[128][68];   // [k][node], padded for float4 + banks
    __shared__ float Ws[128][132];  // [k][o], padded

    int tid = threadIdx.x;
    int tn  = tid & 15;        // node-thread (x4 nodes)
    int to  = tid >> 4;        // out-thread  (x8 outs)
    int n0  = blockIdx.x * 64;
    int o0  = to * 8;

    // stage H tile transposed: Hs[k][r] = in[n0+r][k]
    for (int idx = tid; idx < 2048; idx += 256) {
        int r  = idx & 63;
        int c4 = idx >> 6;
        float4 v = make_float4(0.f, 0.f, 0.f, 0.f);
        if (n0 + r < N)
            v = *(const float4*)&in[(size_t)(n0 + r) * D + c4 * 4];
        Hs[c4 * 4 + 0][r] = v.x;
        Hs[c4 * 4 + 1][r] = v.y;
        Hs[c4 * 4 + 2][r] = v.z;
        Hs[c4 * 4 + 3][r] = v.w;
    }

    auto load_w = [&](const float* __restrict__ Wg) {
        for (int idx = tid; idx < 4096; idx += 256) {
            int o  = idx & 127;
            int k4 = idx >> 7;
            float4 v = *(const float4*)&Wg[o * D + k4 * 4];
            Ws[k4 * 4 + 0][o] = v.x;
            Ws[k4 * 4 + 1][o] = v.y;
            Ws[k4 * 4 + 2][o] = v.z;
            Ws[k4 * 4 + 3][o] = v.w;
        }
    };

    auto compute = [&](float (&res)[4][8]) {
        #pragma unroll
        for (int i = 0; i < 4; ++i)
            #pragma unroll
            for (int j = 0; j < 8; ++j) res[i][j] = 0.f;
        #pragma unroll 4
        for (int k = 0; k < D; ++k) {
            float4 hv = *(const float4*)&Hs[k][tn * 4];
            float4 wa = *(const float4*)&Ws[k][o0];
            float4 wb = *(const float4*)&Ws[k][o0 + 4];
            float hh[4] = {hv.x, hv.y, hv.z, hv.w};
            float wf[8] = {wa.x, wa.y, wa.z, wa.w, wb.x, wb.y, wb.z, wb.w};
            #pragma unroll
            for (int i = 0; i < 4; ++i)
                #pragma unroll
                for (int j = 0; j < 8; ++j)
                    res[i][j] = fmaf(hh[i], wf[j], res[i][j]);
        }
    };

    float acc[4][8];
    float bsave[4][8];

    // ---- W1 -> a_out ----
    load_w(W1);
    __syncthreads();            // covers Hs + Ws
    compute(acc);
    {
        float4 ba = *(const float4*)&b1[o0];
        float4 bb = *(const float4*)&b1[o0 + 4];
        float bf[8] = {ba.x, ba.y, ba.z, ba.w, bb.x, bb.y, bb.z, bb.w};
        #pragma unroll
        for (int i = 0; i < 4; ++i) {
            int row = n0 + tn * 4 + i;
            if (row < N) {
                float4 r0 = make_float4(acc[i][0] + bf[0], acc[i][1] + bf[1],
                                        acc[i][2] + bf[2], acc[i][3] + bf[3]);
                float4 r1 = make_float4(acc[i][4] + bf[4], acc[i][5] + bf[5],
                                        acc[i][6] + bf[6], acc[i][7] + bf[7]);
                *(float4*)&a_out[(size_t)row * D + o0]     = r0;
                *(float4*)&a_out[(size_t)row * D + o0 + 4] = r1;
            }
        }
    }
    __syncthreads();            // all reads of Ws done

    // ---- W2 -> bsave ----
    load_w(W2);
    __syncthreads();
    compute(bsave);
    __syncthreads();

    // ---- W3 -> base_out ----
    load_w(W3);
    __syncthreads();
    compute(acc);
    {
        float4 ba = *(const float4*)&b3[o0];
        float4 bb = *(const float4*)&b3[o0 + 4];
        float bf[8] = {ba.x, ba.y, ba.z, ba.w, bb.x, bb.y, bb.z, bb.w};
        #pragma unroll
        for (int i = 0; i < 4; ++i) {
            int row = n0 + tn * 4 + i;
            if (row < N) {
                float sv = sdeg[row];
                float4 r0 = make_float4(
                    acc[i][0] + bf[0] - sv * bsave[i][0],
                    acc[i][1] + bf[1] - sv * bsave[i][1],
                    acc[i][2] + bf[2] - sv * bsave[i][2],
                    acc[i][3] + bf[3] - sv * bsave[i][3]);
                float4 r1 = make_float4(
                    acc[i][4] + bf[4] - sv * bsave[i][4],
                    acc[i][5] + bf[5] - sv * bsave[i][5],
                    acc[i][6] + bf[6] - sv * bsave[i][6],
                    acc[i][7] + bf[7] - sv * bsave[i][7]);
                *(float4*)&base_out[(size_t)row * D + o0]     = r0;
                *(float4*)&base_out[(size_t)row * D + o0 + 4] = r1;
            }
        }
    }
}

// ---------------- CSR aggregate + activation ----------------
// out[i] = act(base[i] + sum_{e in row i} ew_s[e] * a[src_s[e]])
// one wave per node, lane handles 2 floats (512B coalesced row loads)

__global__ __launch_bounds__(256) void agg_kernel(
    const float* __restrict__ a, const float* __restrict__ base,
    const int* __restrict__ row_off, const int* __restrict__ src_s,
    const float* __restrict__ ew_s, float* __restrict__ out,
    int N, int last)
{
    int wid  = threadIdx.x >> 6;
    int lane = threadIdx.x & 63;
    int node = __builtin_amdgcn_readfirstlane(blockIdx.x * 4 + wid);
    if (node >= N) return;
    int l2 = lane * 2;

    float2 acc = *(const float2*)&base[node * D + l2];
    int beg = row_off[node];
    int end = row_off[node + 1];

    int e = beg;
    for (; e + 4 <= end; e += 4) {
        int   s0 = src_s[e + 0], s1 = src_s[e + 1];
        int   s2 = src_s[e + 2], s3 = src_s[e + 3];
        float w0 = ew_s[e + 0], w1 = ew_s[e + 1];
        float w2 = ew_s[e + 2], w3 = ew_s[e + 3];
        float2 v0 = *(const float2*)&a[s0 * D + l2];
        float2 v1 = *(const float2*)&a[s1 * D + l2];
        float2 v2 = *(const float2*)&a[s2 * D + l2];
        float2 v3 = *(const float2*)&a[s3 * D + l2];
        acc.x = fmaf(w0, v0.x, acc.x); acc.y = fmaf(w0, v0.y, acc.y);
        acc.x = fmaf(w1, v1.x, acc.x); acc.y = fmaf(w1, v1.y, acc.y);
        acc.x = fmaf(w2, v2.x, acc.x); acc.y = fmaf(w2, v2.y, acc.y);
        acc.x = fmaf(w3, v3.x, acc.x); acc.y = fmaf(w3, v3.y, acc.y);
    }
    for (; e < end; ++e) {
        int   s0 = src_s[e];
        float w0 = ew_s[e];
        float2 v0 = *(const float2*)&a[s0 * D + l2];
        acc.x = fmaf(w0, v0.x, acc.x); acc.y = fmaf(w0, v0.y, acc.y);
    }

    // leaky relu 0.1
    acc.x = acc.x >= 0.f ? acc.x : 0.1f * acc.x;
    acc.y = acc.y >= 0.f ? acc.y : 0.1f * acc.y;
    if (last) {
        acc.x = 1.f / (1.f + __expf(-acc.x));
        acc.y = 1.f / (1.f + __expf(-acc.y));
    }
    *(float2*)&out[node * D + l2] = acc;
}

// ---------------- launch ----------------

extern "C" void kernel_launch(void* const* d_in, const int* in_sizes, int n_in,
                              void* d_out, int out_size, void* d_ws, size_t ws_size,
                              hipStream_t stream) {
    const float* x   = (const float*)d_in[0];
    const int*   ei  = (const int*)d_in[1];
    const float* ew  = (const float*)d_in[2];
    const float* iW1 = (const float*)d_in[3];
    const float* ib1 = (const float*)d_in[4];
    const float* iW2 = (const float*)d_in[5];
    const float* iW3 = (const float*)d_in[6];
    const float* ib3 = (const float*)d_in[7];
    const float* mW1 = (const float*)d_in[8];
    const float* mb1 = (const float*)d_in[9];
    const float* mW2 = (const float*)d_in[10];
    const float* mW3 = (const float*)d_in[11];
    const float* mb3 = (const float*)d_in[12];
    const float* oW1 = (const float*)d_in[13];
    const float* ob1 = (const float*)d_in[14];
    const float* oW2 = (const float*)d_in[15];
    const float* oW3 = (const float*)d_in[16];
    const float* ob3 = (const float*)d_in[17];

    int N = in_sizes[0] / D;
    int E = in_sizes[2];
    const int* src = ei;
    const int* dst = ei + E;

    char* wsp = (char*)d_ws;
    size_t off = 0;
    auto alloc = [&](size_t bytes) -> void* {
        void* p = wsp + off;
        off += (bytes + 255) & ~(size_t)255;
        return p;
    };
    float* h       = (float*)alloc((size_t)N * D * 4);
    float* a       = (float*)alloc((size_t)N * D * 4);
    float* sdeg    = (float*)alloc((size_t)N * 4);
    int*   deg     = (int*)alloc((size_t)N * 4);
    int*   row_off = (int*)alloc((size_t)(N + 1) * 4);
    int*   cursor  = (int*)alloc((size_t)N * 4);
    int*   src_s   = (int*)alloc((size_t)E * 4);
    float* ew_s    = (float*)alloc((size_t)E * 4);

    hipMemsetAsync(sdeg, 0, (size_t)N * 4, stream);
    hipMemsetAsync(deg, 0, (size_t)N * 4, stream);

    int eblocks = (E + 255) / 256;
    count_kernel<<<eblocks, 256, 0, stream>>>(dst, ew, deg, sdeg, E);
    scan_kernel<<<1, 1024, 0, stream>>>(deg, row_off, cursor, N);
    scatter_kernel<<<eblocks, 256, 0, stream>>>(src, dst, ew, cursor, src_s, ew_s, E);

    int gblocks = (N + 63) / 64;
    int ablocks = (N + 3) / 4;

    // layer 1 (in)
    gemm_kernel<<<gblocks, 256, 0, stream>>>(x, iW1, ib1, iW2, iW3, ib3, sdeg, a, h, N);
    agg_kernel<<<ablocks, 256, 0, stream>>>(a, h, row_off, src_s, ew_s, h, N, 0);
    // layers 2..3 (mid, shared weights)
    for (int l = 0; l < 2; ++l) {
        gemm_kernel<<<gblocks, 256, 0, stream>>>(h, mW1, mb1, mW2, mW3, mb3, sdeg, a, h, N);
        agg_kernel<<<ablocks, 256, 0, stream>>>(a, h, row_off, src_s, ew_s, h, N, 0);
    }
    // layer 4 (out) -> d_out with sigmoid
    gemm_kernel<<<gblocks, 256, 0, stream>>>(h, oW1, ob1, oW2, oW3, ob3, sdeg, a, h, N);
    agg_kernel<<<ablocks, 256, 0, stream>>>(a, h, row_off, src_s, ew_s, (float*)d_out, N, 1);
}

// Round 3
// 1184.461 us; speedup vs baseline: 1.1233x; 1.1233x over previous
//
#include <hip/hip_runtime.h>
#include <math.h>

#define D 128

// ---------------- preprocessing ----------------

__global__ __launch_bounds__(256) void count_kernel(
    const int* __restrict__ dst, const float* __restrict__ ew,
    int* __restrict__ deg, float* __restrict__ sacc, int E)
{
    int e = blockIdx.x * 256 + threadIdx.x;
    if (e < E) {
        int d = dst[e];
        atomicAdd(&deg[d], 1);
        atomicAdd(&sacc[d], ew[e]);
    }
}

__global__ __launch_bounds__(1024) void scan_kernel(
    const int* __restrict__ deg, int* __restrict__ row_off,
    int* __restrict__ cursor, int n)
{
    __shared__ int wsum[16];
    int tid  = threadIdx.x;
    int lane = tid & 63;
    int wid  = tid >> 6;
    int carry = 0;
    for (int base = 0; base < n; base += 1024) {
        int i = base + tid;
        int v = (i < n) ? deg[i] : 0;
        int x = v;
        #pragma unroll
        for (int off = 1; off < 64; off <<= 1) {
            int t = __shfl_up(x, off);
            if (lane >= off) x += t;
        }
        __syncthreads();                 // protect wsum from prev-iter readers
        if (lane == 63) wsum[wid] = x;
        __syncthreads();
        if (tid < 16) {
            int y = wsum[tid];
            #pragma unroll
            for (int off = 1; off < 16; off <<= 1) {
                int t = __shfl_up(y, off, 16);
                if (tid >= off) y += t;
            }
            wsum[tid] = y;               // inclusive over waves
        }
        __syncthreads();
        int wexcl = wid ? wsum[wid - 1] : 0;
        int excl  = carry + wexcl + x - v;
        if (i < n) { row_off[i] = excl; cursor[i] = excl; }
        carry += wsum[15];
    }
    if (tid == 0) row_off[n] = carry;
}

__global__ __launch_bounds__(256) void scatter_kernel(
    const int* __restrict__ src, const int* __restrict__ dst,
    const float* __restrict__ ew, int* __restrict__ cursor,
    int* __restrict__ src_s, float* __restrict__ ew_s, int E)
{
    int e = blockIdx.x * 256 + threadIdx.x;
    if (e < E) {
        int d = dst[e];
        int pos = atomicAdd(&cursor[d], 1);
        src_s[pos] = src[e];
        ew_s[pos]  = ew[e];
    }
}

// ---------------- fused 3-matmul per layer ----------------
// a_out[n]    = W1 h[n] + b1
// base_out[n] = (W3 h[n] + b3) - s[n] * (W2 h[n])
// block: 256 threads, 64 nodes; thread tile 4 nodes x 8 outs.
// Only the transposed H tile lives in LDS (35KB -> 4 blocks/CU), reused by
// all 3 passes with ONE barrier. W streamed from global (L1/L2-hot; 16
// lanes broadcast-share each address). Inner loop does 8 outs in 2 groups
// of 4 to keep VGPR <= 128.

__global__ __launch_bounds__(256, 4) void gemm_kernel(
    const float* __restrict__ in, const float* __restrict__ W1,
    const float* __restrict__ b1, const float* __restrict__ W2,
    const float* __restrict__ W3, const float* __restrict__ b3,
    const float* __restrict__ sdeg, float* __restrict__ a_out,
    float* __restrict__ base_out, int N)
{
    __shared__ float Hs[128][68];   // [k][node], padded

    int tid = threadIdx.x;
    int tn  = tid & 15;        // node-thread (x4 nodes)
    int to  = tid >> 4;        // out-thread  (x8 outs)
    int n0  = blockIdx.x * 64;
    int o0  = to * 8;

    // stage H tile transposed: Hs[k][r] = in[n0+r][k]
    for (int idx = tid; idx < 2048; idx += 256) {
        int r  = idx & 63;
        int c4 = idx >> 6;
        float4 v = make_float4(0.f, 0.f, 0.f, 0.f);
        if (n0 + r < N)
            v = *(const float4*)&in[(size_t)(n0 + r) * D + c4 * 4];
        Hs[c4 * 4 + 0][r] = v.x;
        Hs[c4 * 4 + 1][r] = v.y;
        Hs[c4 * 4 + 2][r] = v.z;
        Hs[c4 * 4 + 3][r] = v.w;
    }
    __syncthreads();           // ONLY barrier: Hs is read-only afterwards

    // one k-chunked pass over a weight matrix, accumulating into res
    auto pass = [&](const float* __restrict__ Wg, float (&res)[4][8]) {
        for (int kc = 0; kc < D; kc += 4) {
            float4 hv[4];
            #pragma unroll
            for (int kk = 0; kk < 4; ++kk)
                hv[kk] = *(const float4*)&Hs[kc + kk][tn * 4];
            #pragma unroll
            for (int g = 0; g < 2; ++g) {          // 2 groups of 4 outs
                float4 w[4];
                #pragma unroll
                for (int j = 0; j < 4; ++j)
                    w[j] = *(const float4*)&Wg[(o0 + g * 4 + j) * D + kc];
                #pragma unroll
                for (int kk = 0; kk < 4; ++kk) {
                    float hh[4] = {hv[kk].x, hv[kk].y, hv[kk].z, hv[kk].w};
                    #pragma unroll
                    for (int j = 0; j < 4; ++j) {
                        float wf = ((const float*)&w[j])[kk];
                        #pragma unroll
                        for (int i = 0; i < 4; ++i)
                            res[i][g * 4 + j] = fmaf(hh[i], wf, res[i][g * 4 + j]);
                    }
                }
            }
        }
    };

    float acc[4][8];

    // ---- pass 1: W1 -> a_out ----
    #pragma unroll
    for (int i = 0; i < 4; ++i)
        #pragma unroll
        for (int j = 0; j < 8; ++j) acc[i][j] = 0.f;
    pass(W1, acc);
    {
        float4 ba = *(const float4*)&b1[o0];
        float4 bb = *(const float4*)&b1[o0 + 4];
        float bf[8] = {ba.x, ba.y, ba.z, ba.w, bb.x, bb.y, bb.z, bb.w};
        #pragma unroll
        for (int i = 0; i < 4; ++i) {
            int row = n0 + tn * 4 + i;
            if (row < N) {
                float4 r0 = make_float4(acc[i][0] + bf[0], acc[i][1] + bf[1],
                                        acc[i][2] + bf[2], acc[i][3] + bf[3]);
                float4 r1 = make_float4(acc[i][4] + bf[4], acc[i][5] + bf[5],
                                        acc[i][6] + bf[6], acc[i][7] + bf[7]);
                *(float4*)&a_out[(size_t)row * D + o0]     = r0;
                *(float4*)&a_out[(size_t)row * D + o0 + 4] = r1;
            }
        }
    }

    // ---- pass 2: W2 -> acc; scale by -s ----
    #pragma unroll
    for (int i = 0; i < 4; ++i)
        #pragma unroll
        for (int j = 0; j < 8; ++j) acc[i][j] = 0.f;
    pass(W2, acc);
    {
        float sv[4];
        #pragma unroll
        for (int i = 0; i < 4; ++i) {
            int row = n0 + tn * 4 + i;
            sv[i] = (row < N) ? sdeg[row] : 0.f;
        }
        #pragma unroll
        for (int i = 0; i < 4; ++i)
            #pragma unroll
            for (int j = 0; j < 8; ++j)
                acc[i][j] = -sv[i] * acc[i][j];
    }

    // ---- pass 3: W3 accumulates on top; +b3 -> base_out ----
    pass(W3, acc);
    {
        float4 ba = *(const float4*)&b3[o0];
        float4 bb = *(const float4*)&b3[o0 + 4];
        float bf[8] = {ba.x, ba.y, ba.z, ba.w, bb.x, bb.y, bb.z, bb.w};
        #pragma unroll
        for (int i = 0; i < 4; ++i) {
            int row = n0 + tn * 4 + i;
            if (row < N) {
                float4 r0 = make_float4(acc[i][0] + bf[0], acc[i][1] + bf[1],
                                        acc[i][2] + bf[2], acc[i][3] + bf[3]);
                float4 r1 = make_float4(acc[i][4] + bf[4], acc[i][5] + bf[5],
                                        acc[i][6] + bf[6], acc[i][7] + bf[7]);
                *(float4*)&base_out[(size_t)row * D + o0]     = r0;
                *(float4*)&base_out[(size_t)row * D + o0 + 4] = r1;
            }
        }
    }
}

// ---------------- CSR aggregate + activation ----------------
// out[i] = act(base[i] + sum_{e in row i} ew_s[e] * a[src_s[e]])
// one wave per node, lane handles 2 floats (512B coalesced row loads)

__global__ __launch_bounds__(256) void agg_kernel(
    const float* __restrict__ a, const float* __restrict__ base,
    const int* __restrict__ row_off, const int* __restrict__ src_s,
    const float* __restrict__ ew_s, float* __restrict__ out,
    int N, int last)
{
    int wid  = threadIdx.x >> 6;
    int lane = threadIdx.x & 63;
    int node = __builtin_amdgcn_readfirstlane(blockIdx.x * 4 + wid);
    if (node >= N) return;
    int l2 = lane * 2;

    float2 acc = *(const float2*)&base[(size_t)node * D + l2];
    int beg = row_off[node];
    int end = row_off[node + 1];

    int e = beg;
    for (; e + 8 <= end; e += 8) {
        int   s[8];
        float w[8];
        #pragma unroll
        for (int i = 0; i < 8; ++i) { s[i] = src_s[e + i]; w[i] = ew_s[e + i]; }
        #pragma unroll
        for (int i = 0; i < 8; ++i) {
            float2 v = *(const float2*)&a[(size_t)s[i] * D + l2];
            acc.x = fmaf(w[i], v.x, acc.x);
            acc.y = fmaf(w[i], v.y, acc.y);
        }
    }
    for (; e < end; ++e) {
        int   s0 = src_s[e];
        float w0 = ew_s[e];
        float2 v = *(const float2*)&a[(size_t)s0 * D + l2];
        acc.x = fmaf(w0, v.x, acc.x);
        acc.y = fmaf(w0, v.y, acc.y);
    }

    // leaky relu 0.1
    acc.x = acc.x >= 0.f ? acc.x : 0.1f * acc.x;
    acc.y = acc.y >= 0.f ? acc.y : 0.1f * acc.y;
    if (last) {
        acc.x = 1.f / (1.f + __expf(-acc.x));
        acc.y = 1.f / (1.f + __expf(-acc.y));
    }
    *(float2*)&out[(size_t)node * D + l2] = acc;
}

// ---------------- launch ----------------

extern "C" void kernel_launch(void* const* d_in, const int* in_sizes, int n_in,
                              void* d_out, int out_size, void* d_ws, size_t ws_size,
                              hipStream_t stream) {
    const float* x   = (const float*)d_in[0];
    const int*   ei  = (const int*)d_in[1];
    const float* ew  = (const float*)d_in[2];
    const float* iW1 = (const float*)d_in[3];
    const float* ib1 = (const float*)d_in[4];
    const float* iW2 = (const float*)d_in[5];
    const float* iW3 = (const float*)d_in[6];
    const float* ib3 = (const float*)d_in[7];
    const float* mW1 = (const float*)d_in[8];
    const float* mb1 = (const float*)d_in[9];
    const float* mW2 = (const float*)d_in[10];
    const float* mW3 = (const float*)d_in[11];
    const float* mb3 = (const float*)d_in[12];
    const float* oW1 = (const float*)d_in[13];
    const float* ob1 = (const float*)d_in[14];
    const float* oW2 = (const float*)d_in[15];
    const float* oW3 = (const float*)d_in[16];
    const float* ob3 = (const float*)d_in[17];

    int N = in_sizes[0] / D;
    int E = in_sizes[2];
    const int* src = ei;
    const int* dst = ei + E;

    char* wsp = (char*)d_ws;
    size_t off = 0;
    auto alloc = [&](size_t bytes) -> void* {
        void* p = wsp + off;
        off += (bytes + 255) & ~(size_t)255;
        return p;
    };
    float* h       = (float*)alloc((size_t)N * D * 4);
    float* base    = (float*)alloc((size_t)N * D * 4);
    float* a       = (float*)alloc((size_t)N * D * 4);
    float* sdeg    = (float*)alloc((size_t)N * 4);
    int*   deg     = (int*)alloc((size_t)N * 4);
    int*   row_off = (int*)alloc((size_t)(N + 1) * 4);
    int*   cursor  = (int*)alloc((size_t)N * 4);
    int*   src_s   = (int*)alloc((size_t)E * 4);
    float* ew_s    = (float*)alloc((size_t)E * 4);

    hipMemsetAsync(sdeg, 0, (size_t)N * 4, stream);
    hipMemsetAsync(deg, 0, (size_t)N * 4, stream);

    int eblocks = (E + 255) / 256;
    count_kernel<<<eblocks, 256, 0, stream>>>(dst, ew, deg, sdeg, E);
    scan_kernel<<<1, 1024, 0, stream>>>(deg, row_off, cursor, N);
    scatter_kernel<<<eblocks, 256, 0, stream>>>(src, dst, ew, cursor, src_s, ew_s, E);

    int gblocks = (N + 63) / 64;
    int ablocks = (N + 3) / 4;

    // layer 1 (in)
    gemm_kernel<<<gblocks, 256, 0, stream>>>(x, iW1, ib1, iW2, iW3, ib3, sdeg, a, h, N);
    agg_kernel<<<ablocks, 256, 0, stream>>>(a, h, row_off, src_s, ew_s, h, N, 0);
    // wait: gemm reads h? No: layer1 reads x. agg writes h. OK.
    // layers 2..3 (mid, shared weights)
    for (int l = 0; l < 2; ++l) {
        gemm_kernel<<<gblocks, 256, 0, stream>>>(h, mW1, mb1, mW2, mW3, mb3, sdeg, a, base, N);
        agg_kernel<<<ablocks, 256, 0, stream>>>(a, base, row_off, src_s, ew_s, h, N, 0);
    }
    // layer 4 (out) -> d_out with sigmoid
    gemm_kernel<<<gblocks, 256, 0, stream>>>(h, oW1, ob1, oW2, oW3, ob3, sdeg, a, base, N);
    agg_kernel<<<ablocks, 256, 0, stream>>>(a, base, row_off, src_s, ew_s, (float*)d_out, N, 1);
}

// Round 4
// 1103.533 us; speedup vs baseline: 1.2057x; 1.0733x over previous
//
#include <hip/hip_runtime.h>
#include <math.h>

#define D 128

// ---------------- preprocessing ----------------

__global__ __launch_bounds__(256) void count_kernel(
    const int* __restrict__ dst, int* __restrict__ deg, int E)
{
    int e = blockIdx.x * 256 + threadIdx.x;
    if (e < E) atomicAdd(&deg[dst[e]], 1);
}

__global__ __launch_bounds__(1024) void scan_kernel(
    const int* __restrict__ deg, int* __restrict__ row_off,
    int* __restrict__ cursor, int n)
{
    __shared__ int wsum[16];
    int tid  = threadIdx.x;
    int lane = tid & 63;
    int wid  = tid >> 6;
    int carry = 0;
    for (int base = 0; base < n; base += 1024) {
        int i = base + tid;
        int v = (i < n) ? deg[i] : 0;
        int x = v;
        #pragma unroll
        for (int off = 1; off < 64; off <<= 1) {
            int t = __shfl_up(x, off);
            if (lane >= off) x += t;
        }
        __syncthreads();                 // protect wsum from prev-iter readers
        if (lane == 63) wsum[wid] = x;
        __syncthreads();
        if (tid < 16) {
            int y = wsum[tid];
            #pragma unroll
            for (int off = 1; off < 16; off <<= 1) {
                int t = __shfl_up(y, off, 16);
                if (tid >= off) y += t;
            }
            wsum[tid] = y;               // inclusive over waves
        }
        __syncthreads();
        int wexcl = wid ? wsum[wid - 1] : 0;
        int excl  = carry + wexcl + x - v;
        if (i < n) { row_off[i] = excl; cursor[i] = excl; }
        carry += wsum[15];
    }
    if (tid == 0) row_off[n] = carry;
}

// one filtered pass: append edges with src in [lo,hi) -> rows end up
// grouped by src-chunk (coarse src sort for gather locality)
__global__ __launch_bounds__(256) void scatter_kernel(
    const int* __restrict__ src, const int* __restrict__ dst,
    const float* __restrict__ ew, int* __restrict__ cursor,
    int2* __restrict__ edge_s, int E, int lo, int hi)
{
    int e = blockIdx.x * 256 + threadIdx.x;
    if (e < E) {
        int s = src[e];
        if (s >= lo && s < hi) {
            int pos = atomicAdd(&cursor[dst[e]], 1);
            edge_s[pos] = make_int2(s, __float_as_int(ew[e]));
        }
    }
}

// sdeg[i] = sum of ew over row i (replaces the float atomic in count)
__global__ __launch_bounds__(256) void sdeg_kernel(
    const int* __restrict__ row_off, const int2* __restrict__ edge_s,
    float* __restrict__ sdeg, int N)
{
    int lane = threadIdx.x & 63;
    int node = blockIdx.x * 4 + (threadIdx.x >> 6);
    if (node >= N) return;
    int beg = row_off[node], end = row_off[node + 1];
    float s = 0.f;
    for (int e = beg + lane; e < end; e += 64)
        s += __int_as_float(edge_s[e].y);
    #pragma unroll
    for (int off = 32; off; off >>= 1) s += __shfl_xor(s, off);
    if (lane == 0) sdeg[node] = s;
}

// ---------------- fused 3-matmul per layer ----------------
// aA/aB[n] = halves of (W1 h[n] + b1)   (compact 64-wide arrays)
// base_out[n] = (W3 h[n] + b3) - s[n] * (W2 h[n])

__global__ __launch_bounds__(256, 4) void gemm_kernel(
    const float* __restrict__ in, const float* __restrict__ W1,
    const float* __restrict__ b1, const float* __restrict__ W2,
    const float* __restrict__ W3, const float* __restrict__ b3,
    const float* __restrict__ sdeg, float* __restrict__ aA,
    float* __restrict__ aB, float* __restrict__ base_out, int N)
{
    __shared__ float Hs[128][68];   // [k][node], padded

    int tid = threadIdx.x;
    int tn  = tid & 15;        // node-thread (x4 nodes)
    int to  = tid >> 4;        // out-thread  (x8 outs)
    int n0  = blockIdx.x * 64;
    int o0  = to * 8;

    for (int idx = tid; idx < 2048; idx += 256) {
        int r  = idx & 63;
        int c4 = idx >> 6;
        float4 v = make_float4(0.f, 0.f, 0.f, 0.f);
        if (n0 + r < N)
            v = *(const float4*)&in[(size_t)(n0 + r) * D + c4 * 4];
        Hs[c4 * 4 + 0][r] = v.x;
        Hs[c4 * 4 + 1][r] = v.y;
        Hs[c4 * 4 + 2][r] = v.z;
        Hs[c4 * 4 + 3][r] = v.w;
    }
    __syncthreads();           // ONLY barrier: Hs read-only afterwards

    auto pass = [&](const float* __restrict__ Wg, float (&res)[4][8]) {
        for (int kc = 0; kc < D; kc += 4) {
            float4 hv[4];
            #pragma unroll
            for (int kk = 0; kk < 4; ++kk)
                hv[kk] = *(const float4*)&Hs[kc + kk][tn * 4];
            #pragma unroll
            for (int g = 0; g < 2; ++g) {
                float4 w[4];
                #pragma unroll
                for (int j = 0; j < 4; ++j)
                    w[j] = *(const float4*)&Wg[(o0 + g * 4 + j) * D + kc];
                #pragma unroll
                for (int kk = 0; kk < 4; ++kk) {
                    float hh[4] = {hv[kk].x, hv[kk].y, hv[kk].z, hv[kk].w};
                    #pragma unroll
                    for (int j = 0; j < 4; ++j) {
                        float wf = ((const float*)&w[j])[kk];
                        #pragma unroll
                        for (int i = 0; i < 4; ++i)
                            res[i][g * 4 + j] = fmaf(hh[i], wf, res[i][g * 4 + j]);
                    }
                }
            }
        }
    };

    float acc[4][8];

    // ---- pass 1: W1 -> aA/aB (compact halves) ----
    #pragma unroll
    for (int i = 0; i < 4; ++i)
        #pragma unroll
        for (int j = 0; j < 8; ++j) acc[i][j] = 0.f;
    pass(W1, acc);
    {
        float4 ba = *(const float4*)&b1[o0];
        float4 bb = *(const float4*)&b1[o0 + 4];
        float bf[8] = {ba.x, ba.y, ba.z, ba.w, bb.x, bb.y, bb.z, bb.w};
        float* ah = (o0 < 64) ? aA : aB;
        int    oh = o0 & 63;
        #pragma unroll
        for (int i = 0; i < 4; ++i) {
            int row = n0 + tn * 4 + i;
            if (row < N) {
                float4 r0 = make_float4(acc[i][0] + bf[0], acc[i][1] + bf[1],
                                        acc[i][2] + bf[2], acc[i][3] + bf[3]);
                float4 r1 = make_float4(acc[i][4] + bf[4], acc[i][5] + bf[5],
                                        acc[i][6] + bf[6], acc[i][7] + bf[7]);
                *(float4*)&ah[(size_t)row * 64 + oh]     = r0;
                *(float4*)&ah[(size_t)row * 64 + oh + 4] = r1;
            }
        }
    }

    // ---- pass 2: W2 -> acc; scale by -s ----
    #pragma unroll
    for (int i = 0; i < 4; ++i)
        #pragma unroll
        for (int j = 0; j < 8; ++j) acc[i][j] = 0.f;
    pass(W2, acc);
    {
        float sv[4];
        #pragma unroll
        for (int i = 0; i < 4; ++i) {
            int row = n0 + tn * 4 + i;
            sv[i] = (row < N) ? sdeg[row] : 0.f;
        }
        #pragma unroll
        for (int i = 0; i < 4; ++i)
            #pragma unroll
            for (int j = 0; j < 8; ++j)
                acc[i][j] = -sv[i] * acc[i][j];
    }

    // ---- pass 3: W3 accumulates; +b3 -> base_out ----
    pass(W3, acc);
    {
        float4 ba = *(const float4*)&b3[o0];
        float4 bb = *(const float4*)&b3[o0 + 4];
        float bf[8] = {ba.x, ba.y, ba.z, ba.w, bb.x, bb.y, bb.z, bb.w};
        #pragma unroll
        for (int i = 0; i < 4; ++i) {
            int row = n0 + tn * 4 + i;
            if (row < N) {
                float4 r0 = make_float4(acc[i][0] + bf[0], acc[i][1] + bf[1],
                                        acc[i][2] + bf[2], acc[i][3] + bf[3]);
                float4 r1 = make_float4(acc[i][4] + bf[4], acc[i][5] + bf[5],
                                        acc[i][6] + bf[6], acc[i][7] + bf[7]);
                *(float4*)&base_out[(size_t)row * D + o0]     = r0;
                *(float4*)&base_out[(size_t)row * D + o0 + 4] = r1;
            }
        }
    }
}

// ---------------- CSR aggregate + activation (one 64-feature half) ------
// out[i][hofs+lane] = act(base[i][hofs+lane] + sum_row ew * aH[src][lane])

__global__ __launch_bounds__(256) void agg_kernel(
    const float* __restrict__ aH, const float* __restrict__ base,
    const int* __restrict__ row_off, const int2* __restrict__ edge_s,
    float* __restrict__ out, int N, int hofs, int last)
{
    int lane = threadIdx.x & 63;
    int node = blockIdx.x * 4 + (threadIdx.x >> 6);
    if (node >= N) return;

    float acc = base[(size_t)node * D + hofs + lane];
    int beg = row_off[node];
    int end = row_off[node + 1];

    int e = beg;
    for (; e + 8 <= end; e += 8) {
        int2 ed[8];
        #pragma unroll
        for (int i = 0; i < 8; ++i) ed[i] = edge_s[e + i];
        float v[8];
        #pragma unroll
        for (int i = 0; i < 8; ++i)
            v[i] = aH[(size_t)ed[i].x * 64 + lane];
        #pragma unroll
        for (int i = 0; i < 8; ++i)
            acc = fmaf(__int_as_float(ed[i].y), v[i], acc);
    }
    for (; e < end; ++e) {
        int2 ed = edge_s[e];
        acc = fmaf(__int_as_float(ed.y), aH[(size_t)ed.x * 64 + lane], acc);
    }

    acc = acc >= 0.f ? acc : 0.1f * acc;          // leaky relu 0.1
    if (last) acc = 1.f / (1.f + __expf(-acc));   // sigmoid
    out[(size_t)node * D + hofs + lane] = acc;
}

// ---------------- launch ----------------

extern "C" void kernel_launch(void* const* d_in, const int* in_sizes, int n_in,
                              void* d_out, int out_size, void* d_ws, size_t ws_size,
                              hipStream_t stream) {
    const float* x   = (const float*)d_in[0];
    const int*   ei  = (const int*)d_in[1];
    const float* ew  = (const float*)d_in[2];
    const float* iW1 = (const float*)d_in[3];
    const float* ib1 = (const float*)d_in[4];
    const float* iW2 = (const float*)d_in[5];
    const float* iW3 = (const float*)d_in[6];
    const float* ib3 = (const float*)d_in[7];
    const float* mW1 = (const float*)d_in[8];
    const float* mb1 = (const float*)d_in[9];
    const float* mW2 = (const float*)d_in[10];
    const float* mW3 = (const float*)d_in[11];
    const float* mb3 = (const float*)d_in[12];
    const float* oW1 = (const float*)d_in[13];
    const float* ob1 = (const float*)d_in[14];
    const float* oW2 = (const float*)d_in[15];
    const float* oW3 = (const float*)d_in[16];
    const float* ob3 = (const float*)d_in[17];

    int N = in_sizes[0] / D;
    int E = in_sizes[2];
    const int* src = ei;
    const int* dst = ei + E;

    char* wsp = (char*)d_ws;
    size_t off = 0;
    auto alloc = [&](size_t bytes) -> void* {
        void* p = wsp + off;
        off += (bytes + 255) & ~(size_t)255;
        return p;
    };
    float* h       = (float*)alloc((size_t)N * D * 4);
    float* base    = (float*)alloc((size_t)N * D * 4);
    float* aA      = (float*)alloc((size_t)N * 64 * 4);
    float* aB      = (float*)alloc((size_t)N * 64 * 4);
    float* sdeg    = (float*)alloc((size_t)N * 4);
    int*   deg     = (int*)alloc((size_t)N * 4);
    int*   row_off = (int*)alloc((size_t)(N + 1) * 4);
    int*   cursor  = (int*)alloc((size_t)N * 4);
    int2*  edge_s  = (int2*)alloc((size_t)E * 8);

    hipMemsetAsync(deg, 0, (size_t)N * 4, stream);

    int eblocks = (E + 255) / 256;
    count_kernel<<<eblocks, 256, 0, stream>>>(dst, deg, E);
    scan_kernel<<<1, 1024, 0, stream>>>(deg, row_off, cursor, N);
    // 8 src-chunk passes -> rows grouped by src range (gather locality)
    const int NCHUNK = 8;
    for (int c = 0; c < NCHUNK; ++c) {
        int lo = (int)((long long)N * c / NCHUNK);
        int hi = (int)((long long)N * (c + 1) / NCHUNK);
        scatter_kernel<<<eblocks, 256, 0, stream>>>(src, dst, ew, cursor,
                                                    edge_s, E, lo, hi);
    }
    int ablocks = (N + 3) / 4;
    sdeg_kernel<<<ablocks, 256, 0, stream>>>(row_off, edge_s, sdeg, N);

    int gblocks = (N + 63) / 64;

    // layer 1 (in): reads x
    gemm_kernel<<<gblocks, 256, 0, stream>>>(x, iW1, ib1, iW2, iW3, ib3, sdeg, aA, aB, base, N);
    agg_kernel<<<ablocks, 256, 0, stream>>>(aA, base, row_off, edge_s, h, N, 0, 0);
    agg_kernel<<<ablocks, 256, 0, stream>>>(aB, base, row_off, edge_s, h, N, 64, 0);
    // layers 2..3 (mid, shared weights)
    for (int l = 0; l < 2; ++l) {
        gemm_kernel<<<gblocks, 256, 0, stream>>>(h, mW1, mb1, mW2, mW3, mb3, sdeg, aA, aB, base, N);
        agg_kernel<<<ablocks, 256, 0, stream>>>(aA, base, row_off, edge_s, h, N, 0, 0);
        agg_kernel<<<ablocks, 256, 0, stream>>>(aB, base, row_off, edge_s, h, N, 64, 0);
    }
    // layer 4 (out) -> d_out with sigmoid
    gemm_kernel<<<gblocks, 256, 0, stream>>>(h, oW1, ob1, oW2, oW3, ob3, sdeg, aA, aB, base, N);
    agg_kernel<<<ablocks, 256, 0, stream>>>(aA, base, row_off, edge_s, (float*)d_out, N, 0, 1);
    agg_kernel<<<ablocks, 256, 0, stream>>>(aB, base, row_off, edge_s, (float*)d_out, N, 64, 1);
}

// Round 5
// 1071.380 us; speedup vs baseline: 1.2419x; 1.0300x over previous
//
#include <hip/hip_runtime.h>
#include <math.h>

#define D 128
#define CSH 13   // src-chunk shift: 8192 nodes/chunk -> 7 chunks at N=50000

// ---------------- preprocessing ----------------

// deg2[dst*nchunk + (src>>CSH)] ++
__global__ __launch_bounds__(256) void count_kernel(
    const int* __restrict__ src, const int* __restrict__ dst,
    int* __restrict__ deg2, int E, int nchunk)
{
    int e = blockIdx.x * 256 + threadIdx.x;
    if (e < E) {
        int c = src[e] >> CSH;
        atomicAdd(&deg2[(size_t)dst[e] * nchunk + c], 1);
    }
}

__global__ __launch_bounds__(256) void rowsum_kernel(
    const int* __restrict__ deg2, int* __restrict__ deg, int N, int nchunk)
{
    int i = blockIdx.x * 256 + threadIdx.x;
    if (i < N) {
        int s = 0;
        for (int c = 0; c < nchunk; ++c) s += deg2[(size_t)i * nchunk + c];
        deg[i] = s;
    }
}

__global__ __launch_bounds__(1024) void scan_kernel(
    const int* __restrict__ deg, int* __restrict__ row_off, int n)
{
    __shared__ int wsum[16];
    int tid  = threadIdx.x;
    int lane = tid & 63;
    int wid  = tid >> 6;
    int carry = 0;
    for (int base = 0; base < n; base += 1024) {
        int i = base + tid;
        int v = (i < n) ? deg[i] : 0;
        int x = v;
        #pragma unroll
        for (int off = 1; off < 64; off <<= 1) {
            int t = __shfl_up(x, off);
            if (lane >= off) x += t;
        }
        __syncthreads();
        if (lane == 63) wsum[wid] = x;
        __syncthreads();
        if (tid < 16) {
            int y = wsum[tid];
            #pragma unroll
            for (int off = 1; off < 16; off <<= 1) {
                int t = __shfl_up(y, off, 16);
                if (tid >= off) y += t;
            }
            wsum[tid] = y;
        }
        __syncthreads();
        int wexcl = wid ? wsum[wid - 1] : 0;
        int excl  = carry + wexcl + x - v;
        if (i < n) row_off[i] = excl;
        carry += wsum[15];
    }
    if (tid == 0) row_off[n] = carry;
}

// cursor2[i*nchunk+c] = row_off[i] + prefix of deg2 within row i
__global__ __launch_bounds__(256) void cursor_kernel(
    const int* __restrict__ row_off, const int* __restrict__ deg2,
    int* __restrict__ cursor2, int N, int nchunk)
{
    int i = blockIdx.x * 256 + threadIdx.x;
    if (i < N) {
        int p = row_off[i];
        for (int c = 0; c < nchunk; ++c) {
            cursor2[(size_t)i * nchunk + c] = p;
            p += deg2[(size_t)i * nchunk + c];
        }
    }
}

// single pass: edges land grouped by (dst row, src chunk)
__global__ __launch_bounds__(256) void scatter_kernel(
    const int* __restrict__ src, const int* __restrict__ dst,
    const float* __restrict__ ew, int* __restrict__ cursor2,
    int2* __restrict__ edge_s, int E, int nchunk)
{
    int e = blockIdx.x * 256 + threadIdx.x;
    if (e < E) {
        int s = src[e];
        int pos = atomicAdd(&cursor2[(size_t)dst[e] * nchunk + (s >> CSH)], 1);
        edge_s[pos] = make_int2(s, __float_as_int(ew[e]));
    }
}

// sdeg[i] = sum of ew over row i
__global__ __launch_bounds__(256) void sdeg_kernel(
    const int* __restrict__ row_off, const int2* __restrict__ edge_s,
    float* __restrict__ sdeg, int N)
{
    int lane = threadIdx.x & 63;
    int node = blockIdx.x * 4 + (threadIdx.x >> 6);
    if (node >= N) return;
    int beg = row_off[node], end = row_off[node + 1];
    float s = 0.f;
    for (int e = beg + lane; e < end; e += 64)
        s += __int_as_float(edge_s[e].y);
    #pragma unroll
    for (int off = 32; off; off >>= 1) s += __shfl_xor(s, off);
    if (lane == 0) sdeg[node] = s;
}

// ---------------- fused 3-matmul per layer ----------------
// aA/aB[n] = halves of (W1 h[n] + b1);  base = (W3 h + b3) - s*(W2 h)
// 128 threads, 32 nodes/block (grid 1563 -> ~6 blocks/CU), thread tile
// 4 nodes x 8 outs, double-buffered W prefetch in registers.

__global__ __launch_bounds__(128, 3) void gemm_kernel(
    const float* __restrict__ in, const float* __restrict__ W1,
    const float* __restrict__ b1, const float* __restrict__ W2,
    const float* __restrict__ W3, const float* __restrict__ b3,
    const float* __restrict__ sdeg, float* __restrict__ aA,
    float* __restrict__ aB, float* __restrict__ base_out, int N)
{
    __shared__ float Hs[128][36];   // [k][node], 32 nodes + pad

    int tid = threadIdx.x;
    int tn  = tid & 7;         // 8 node-threads x 4 nodes = 32
    int to  = tid >> 3;        // 16 out-threads x 8 outs = 128
    int n0  = blockIdx.x * 32;
    int o0  = to * 8;

    // coalesced stage: lanes sweep a row's 32 float4s
    for (int idx = tid; idx < 1024; idx += 128) {
        int c4 = idx & 31;
        int r  = idx >> 5;
        float4 v = make_float4(0.f, 0.f, 0.f, 0.f);
        if (n0 + r < N)
            v = *(const float4*)&in[(size_t)(n0 + r) * D + c4 * 4];
        Hs[c4 * 4 + 0][r] = v.x;
        Hs[c4 * 4 + 1][r] = v.y;
        Hs[c4 * 4 + 2][r] = v.z;
        Hs[c4 * 4 + 3][r] = v.w;
    }
    __syncthreads();           // ONLY barrier

    auto loadW = [&](const float* __restrict__ Wg, int kc, float4 (&w)[8]) {
        #pragma unroll
        for (int j = 0; j < 8; ++j)
            w[j] = *(const float4*)&Wg[(size_t)(o0 + j) * D + kc];
    };
    auto fmas = [&](int kc, const float4 (&w)[8], float (&res)[4][8]) {
        float4 hv[4];
        #pragma unroll
        for (int kk = 0; kk < 4; ++kk)
            hv[kk] = *(const float4*)&Hs[kc + kk][tn * 4];
        #pragma unroll
        for (int kk = 0; kk < 4; ++kk) {
            float hh[4] = {hv[kk].x, hv[kk].y, hv[kk].z, hv[kk].w};
            #pragma unroll
            for (int j = 0; j < 8; ++j) {
                float wf = ((const float*)&w[j])[kk];
                #pragma unroll
                for (int i = 0; i < 4; ++i)
                    res[i][j] = fmaf(hh[i], wf, res[i][j]);
            }
        }
    };
    auto pass = [&](const float* __restrict__ Wg, float (&res)[4][8]) {
        float4 wA[8], wB[8];
        loadW(Wg, 0, wA);
        for (int kc = 0; kc < D; kc += 8) {
            loadW(Wg, kc + 4, wB);
            fmas(kc, wA, res);
            if (kc + 8 < D) loadW(Wg, kc + 8, wA);
            fmas(kc + 4, wB, res);
        }
    };

    float acc[4][8];

    // ---- pass 1: W1 -> aA/aB (compact halves) ----
    #pragma unroll
    for (int i = 0; i < 4; ++i)
        #pragma unroll
        for (int j = 0; j < 8; ++j) acc[i][j] = 0.f;
    pass(W1, acc);
    {
        float4 ba = *(const float4*)&b1[o0];
        float4 bb = *(const float4*)&b1[o0 + 4];
        float bf[8] = {ba.x, ba.y, ba.z, ba.w, bb.x, bb.y, bb.z, bb.w};
        float* ah = (o0 < 64) ? aA : aB;
        int    oh = o0 & 63;
        #pragma unroll
        for (int i = 0; i < 4; ++i) {
            int row = n0 + tn * 4 + i;
            if (row < N) {
                float4 r0 = make_float4(acc[i][0] + bf[0], acc[i][1] + bf[1],
                                        acc[i][2] + bf[2], acc[i][3] + bf[3]);
                float4 r1 = make_float4(acc[i][4] + bf[4], acc[i][5] + bf[5],
                                        acc[i][6] + bf[6], acc[i][7] + bf[7]);
                *(float4*)&ah[(size_t)row * 64 + oh]     = r0;
                *(float4*)&ah[(size_t)row * 64 + oh + 4] = r1;
            }
        }
    }

    // ---- pass 2: W2 -> acc; scale by -s ----
    #pragma unroll
    for (int i = 0; i < 4; ++i)
        #pragma unroll
        for (int j = 0; j < 8; ++j) acc[i][j] = 0.f;
    pass(W2, acc);
    {
        float sv[4];
        #pragma unroll
        for (int i = 0; i < 4; ++i) {
            int row = n0 + tn * 4 + i;
            sv[i] = (row < N) ? sdeg[row] : 0.f;
        }
        #pragma unroll
        for (int i = 0; i < 4; ++i)
            #pragma unroll
            for (int j = 0; j < 8; ++j)
                acc[i][j] = -sv[i] * acc[i][j];
    }

    // ---- pass 3: W3 accumulates; +b3 -> base_out ----
    pass(W3, acc);
    {
        float4 ba = *(const float4*)&b3[o0];
        float4 bb = *(const float4*)&b3[o0 + 4];
        float bf[8] = {ba.x, ba.y, ba.z, ba.w, bb.x, bb.y, bb.z, bb.w};
        #pragma unroll
        for (int i = 0; i < 4; ++i) {
            int row = n0 + tn * 4 + i;
            if (row < N) {
                float4 r0 = make_float4(acc[i][0] + bf[0], acc[i][1] + bf[1],
                                        acc[i][2] + bf[2], acc[i][3] + bf[3]);
                float4 r1 = make_float4(acc[i][4] + bf[4], acc[i][5] + bf[5],
                                        acc[i][6] + bf[6], acc[i][7] + bf[7]);
                *(float4*)&base_out[(size_t)row * D + o0]     = r0;
                *(float4*)&base_out[(size_t)row * D + o0 + 4] = r1;
            }
        }
    }
}

// ---------------- CSR aggregate + activation (one 64-feature half) ------

__global__ __launch_bounds__(256) void agg_kernel(
    const float* __restrict__ aH, const float* __restrict__ base,
    const int* __restrict__ row_off, const int2* __restrict__ edge_s,
    float* __restrict__ out, int N, int hofs, int last)
{
    int lane = threadIdx.x & 63;
    int node = blockIdx.x * 4 + (threadIdx.x >> 6);
    if (node >= N) return;

    float acc = base[(size_t)node * D + hofs + lane];
    int beg = row_off[node];
    int end = row_off[node + 1];

    int e = beg;
    if ((e & 1) && e < end) {         // peel to align int4 batches
        int2 ed = edge_s[e];
        acc = fmaf(__int_as_float(ed.y), aH[(size_t)ed.x * 64 + lane], acc);
        ++e;
    }
    for (; e + 16 <= end; e += 16) {  // 16 edges, 8 aligned int4 loads
        int4 ed[8];
        #pragma unroll
        for (int i = 0; i < 8; ++i) ed[i] = *(const int4*)&edge_s[e + i * 2];
        float v[16];
        #pragma unroll
        for (int i = 0; i < 8; ++i) {
            v[2 * i]     = aH[(size_t)ed[i].x * 64 + lane];
            v[2 * i + 1] = aH[(size_t)ed[i].z * 64 + lane];
        }
        #pragma unroll
        for (int i = 0; i < 8; ++i) {
            acc = fmaf(__int_as_float(ed[i].y), v[2 * i], acc);
            acc = fmaf(__int_as_float(ed[i].w), v[2 * i + 1], acc);
        }
    }
    for (; e + 4 <= end; e += 4) {
        int4 e0 = *(const int4*)&edge_s[e];
        int4 e1 = *(const int4*)&edge_s[e + 2];
        float v0 = aH[(size_t)e0.x * 64 + lane];
        float v1 = aH[(size_t)e0.z * 64 + lane];
        float v2 = aH[(size_t)e1.x * 64 + lane];
        float v3 = aH[(size_t)e1.z * 64 + lane];
        acc = fmaf(__int_as_float(e0.y), v0, acc);
        acc = fmaf(__int_as_float(e0.w), v1, acc);
        acc = fmaf(__int_as_float(e1.y), v2, acc);
        acc = fmaf(__int_as_float(e1.w), v3, acc);
    }
    for (; e < end; ++e) {
        int2 ed = edge_s[e];
        acc = fmaf(__int_as_float(ed.y), aH[(size_t)ed.x * 64 + lane], acc);
    }

    acc = acc >= 0.f ? acc : 0.1f * acc;          // leaky relu 0.1
    if (last) acc = 1.f / (1.f + __expf(-acc));   // sigmoid
    out[(size_t)node * D + hofs + lane] = acc;
}

// ---------------- launch ----------------

extern "C" void kernel_launch(void* const* d_in, const int* in_sizes, int n_in,
                              void* d_out, int out_size, void* d_ws, size_t ws_size,
                              hipStream_t stream) {
    const float* x   = (const float*)d_in[0];
    const int*   ei  = (const int*)d_in[1];
    const float* ew  = (const float*)d_in[2];
    const float* iW1 = (const float*)d_in[3];
    const float* ib1 = (const float*)d_in[4];
    const float* iW2 = (const float*)d_in[5];
    const float* iW3 = (const float*)d_in[6];
    const float* ib3 = (const float*)d_in[7];
    const float* mW1 = (const float*)d_in[8];
    const float* mb1 = (const float*)d_in[9];
    const float* mW2 = (const float*)d_in[10];
    const float* mW3 = (const float*)d_in[11];
    const float* mb3 = (const float*)d_in[12];
    const float* oW1 = (const float*)d_in[13];
    const float* ob1 = (const float*)d_in[14];
    const float* oW2 = (const float*)d_in[15];
    const float* oW3 = (const float*)d_in[16];
    const float* ob3 = (const float*)d_in[17];

    int N = in_sizes[0] / D;
    int E = in_sizes[2];
    const int* src = ei;
    const int* dst = ei + E;
    int nchunk = (N + (1 << CSH) - 1) >> CSH;

    char* wsp = (char*)d_ws;
    size_t off = 0;
    auto alloc = [&](size_t bytes) -> void* {
        void* p = wsp + off;
        off += (bytes + 255) & ~(size_t)255;
        return p;
    };
    float* h       = (float*)alloc((size_t)N * D * 4);
    float* base    = (float*)alloc((size_t)N * D * 4);
    float* aA      = (float*)alloc((size_t)N * 64 * 4);
    float* aB      = (float*)alloc((size_t)N * 64 * 4);
    float* sdeg    = (float*)alloc((size_t)N * 4);
    int*   deg     = (int*)alloc((size_t)N * 4);
    int*   deg2    = (int*)alloc((size_t)N * nchunk * 4);
    int*   cursor2 = (int*)alloc((size_t)N * nchunk * 4);
    int*   row_off = (int*)alloc((size_t)(N + 1) * 4);
    int2*  edge_s  = (int2*)alloc((size_t)E * 8);

    hipMemsetAsync(deg2, 0, (size_t)N * nchunk * 4, stream);

    int eblocks = (E + 255) / 256;
    int nblocks = (N + 255) / 256;
    int ablocks = (N + 3) / 4;
    int gblocks = (N + 31) / 32;

    count_kernel<<<eblocks, 256, 0, stream>>>(src, dst, deg2, E, nchunk);
    rowsum_kernel<<<nblocks, 256, 0, stream>>>(deg2, deg, N, nchunk);
    scan_kernel<<<1, 1024, 0, stream>>>(deg, row_off, N);
    cursor_kernel<<<nblocks, 256, 0, stream>>>(row_off, deg2, cursor2, N, nchunk);
    scatter_kernel<<<eblocks, 256, 0, stream>>>(src, dst, ew, cursor2, edge_s, E, nchunk);
    sdeg_kernel<<<ablocks, 256, 0, stream>>>(row_off, edge_s, sdeg, N);

    // layer 1 (in): reads x
    gemm_kernel<<<gblocks, 128, 0, stream>>>(x, iW1, ib1, iW2, iW3, ib3, sdeg, aA, aB, base, N);
    agg_kernel<<<ablocks, 256, 0, stream>>>(aA, base, row_off, edge_s, h, N, 0, 0);
    agg_kernel<<<ablocks, 256, 0, stream>>>(aB, base, row_off, edge_s, h, N, 64, 0);
    // layers 2..3 (mid, shared weights)
    for (int l = 0; l < 2; ++l) {
        gemm_kernel<<<gblocks, 128, 0, stream>>>(h, mW1, mb1, mW2, mW3, mb3, sdeg, aA, aB, base, N);
        agg_kernel<<<ablocks, 256, 0, stream>>>(aA, base, row_off, edge_s, h, N, 0, 0);
        agg_kernel<<<ablocks, 256, 0, stream>>>(aB, base, row_off, edge_s, h, N, 64, 0);
    }
    // layer 4 (out) -> d_out with sigmoid
    gemm_kernel<<<gblocks, 128, 0, stream>>>(h, oW1, ob1, oW2, oW3, ob3, sdeg, aA, aB, base, N);
    agg_kernel<<<ablocks, 256, 0, stream>>>(aA, base, row_off, edge_s, (float*)d_out, N, 0, 1);
    agg_kernel<<<ablocks, 256, 0, stream>>>(aB, base, row_off, edge_s, (float*)d_out, N, 64, 1);
}